// Round 1
// baseline (198.340 us; speedup 1.0000x reference)
//
#include <hip/hip_runtime.h>
#include <hip/hip_fp16.h>

#define R_ 3
#define D_ 7            // 2R+1
#define W_ 49
#define N_ 128
#define K_ 131
#define C_ 21
#define B_ 2
#define NN (N_ * N_)
#define TI_ 16                  // tile rows
#define TJ_ 16                  // tile cols
#define PROWS (TI_ + 2 * R_)    // 22
#define PCOLS (TJ_ + 2 * R_)    // 22
#define PSTR 24                 // LDS row stride (float2 pairs)
#define NELEM (PROWS * PCOLS)   // 484 staged elements
#define LDSP (PROWS * PSTR + 8) // 536 pairs (spare write slot at 532)
#define KC 16                   // k-chunks per tile (131 = 3x9 + 13x8)

typedef __fp16 h2 __attribute__((ext_vector_type(2)));

// Affinity: per-pixel 7x7 window softmax per channel, weighted by cp[k].
// exp(|c-n|) = max(Ec*EnInv, En*EcInv), (E,Einv) pairs staged per element
// (E = exp2(f*mask*log2e)). Lane pairs (2t,2t+1) share a SLOT; h=tid&1 owns
// columns v=2s+h (s=0..3). The h=1,s=3 slot is the phantom v=7 tap: it reads
// a REAL staged element so it MUST be killed explicitly with ph.
//
// NEW vs previous version:
//  * Mask compaction: sel_mask density is 0.5 and unmasked rows of A are
//    zero (reference multiplies by m). ballot+prefix compacts masked pixels
//    of a 16x16 tile into plist; thread-pairs process compacted slots only
//    (slot = tid>>1, plus fixed second pass at slot+128 for the binomial
//    tail). ~50% of tap VALU + LDS reads eliminated.
//  * 16x16 tile: 484-elem halo for 256 pixels (1.9x overstage vs 2.4x).
//  * KC=16 keeps 2048 blocks (8/CU) and same total atomic traffic.
//  * Double-buffered LDS staging: one barrier per k (was two); k+2 global
//    prefetch issues before the tap phase.
// Numerics identical to previous version (f32 taps, f16 ex/Aacc pk_fma).
__global__ __launch_bounds__(256) void rwn_affinity(
    const float* __restrict__ feats,   // [B,K,N,N]
    const int*   __restrict__ mask,    // [B,N,N]
    const float* __restrict__ cp,      // [K]
    float* __restrict__ Aout)          // [B,W,NN] (pre-zeroed)
{
    __shared__ float2 patch2[2][LDSP];
    __shared__ int wsum[4];
    __shared__ unsigned char plist[256];

    const int tile = blockIdx.x;           // 0..63 (8x8 tiles of 16x16)
    const int kc   = blockIdx.y;
    const int b    = blockIdx.z;
    const int tr = tile >> 3, tc = tile & 7;
    const int ti0 = tr * TI_, tj0 = tc * TJ_;

    const int tid = threadIdx.x;
    const int h   = tid & 1;               // column-parity owner within pair

    // ---- hoisted staging setup: thread owns elements tid and 256+tid ----
    const float LOG2E = 1.4426950408889634f;
    int   soff[2];      // clamped global offset
    float swt[2];       // in-bounds * mask * log2e
    float ozw[2];       // 0 for OOB (store zero pair), 1 otherwise
    int   slds[2];      // pair index in LDS
    #pragma unroll
    for (int r = 0; r < 2; ++r) {
        int e = tid + r * 256;
        bool act = (e < NELEM);
        int pr = e / PCOLS, pc = e - pr * PCOLS;
        int mi = ti0 + pr - R_, mj = tj0 + pc - R_;
        bool inb = act && mi >= 0 && mi < N_ && mj >= 0 && mj < N_;
        int cmi = mi < 0 ? 0 : (mi > N_ - 1 ? N_ - 1 : mi);
        int cmj = mj < 0 ? 0 : (mj > N_ - 1 ? N_ - 1 : mj);
        soff[r] = cmi * N_ + cmj;
        swt[r]  = inb ? ((float)mask[b * NN + soff[r]] * LOG2E) : 0.f;
        ozw[r]  = inb ? 1.f : 0.f;
        slds[r] = act ? (pr * PSTR + pc) : (PROWS * PSTR + 4);  // spare slot
    }

    // ---- mask compaction (once per block) ----
    const int mk = mask[b * NN + (ti0 + (tid >> 4)) * N_ + (tj0 + (tid & 15))];
    const unsigned long long bal = __ballot(mk != 0);
    const int lane = tid & 63, wv = tid >> 6;
    if (lane == 0) wsum[wv] = __popcll(bal);

    // zero-init BOTH LDS buffers once: pad cols 22,23 / spare slot stay 0
    for (int e = tid; e < 2 * LDSP; e += 256)
        (&patch2[0][0])[e] = make_float2(0.f, 0.f);

    // k-range (balanced: 3 chunks of 9, 13 of 8) + first prefetch
    const int k0 = kc * 8 + (kc < 3 ? kc : 3);
    const int k1 = k0 + 8 + (kc < 3 ? 1 : 0);
    const float* fb = feats + (size_t)b * K_ * NN;
    const float* fk0 = fb + (size_t)k0 * NN;
    float pr0 = fk0[soff[0]] * swt[0];
    float pr1 = fk0[soff[1]] * swt[1];

    __syncthreads();   // wsum + zero-init visible

    const int nm = wsum[0] + wsum[1] + wsum[2] + wsum[3];
    int pb = 0;
    if (wv > 0) pb += wsum[0];
    if (wv > 1) pb += wsum[1];
    if (wv > 2) pb += wsum[2];
    if (mk) plist[pb + __popcll(bal & ((1ull << lane) - 1ull))] = (unsigned char)tid;

    // stage k0 into buffer 0; prefetch raw k0+1
    patch2[0][slds[0]] = make_float2(ozw[0] * exp2f(pr0), ozw[0] * exp2f(-pr0));
    patch2[0][slds[1]] = make_float2(ozw[1] * exp2f(pr1), ozw[1] * exp2f(-pr1));
    {
        const float* fn = fb + (size_t)(k0 + 1) * NN;   // k-chunks >= 8 long
        pr0 = fn[soff[0]] * swt[0];
        pr1 = fn[soff[1]] * swt[1];
    }
    __syncthreads();   // plist + buf0 ready

    // slot assignment (fixed: slot and slot+128 cover all nm <= 256)
    const int slot = tid >> 1;
    const bool act0 = slot < nm;
    const bool act1 = slot + 128 < nm;
    int cb0 = 0, pg0 = 0, cb1 = 0, pg1 = 0;
    if (act0) {
        int q = plist[slot];        int qi = q >> 4, qj = q & 15;
        cb0 = qi * PSTR + qj;       pg0 = (ti0 + qi) * N_ + (tj0 + qj);
    }
    if (act1) {
        int q = plist[slot + 128];  int qi = q >> 4, qj = q & 15;
        cb1 = qi * PSTR + qj;       pg1 = (ti0 + qi) * N_ + (tj0 + qj);
    }

    const float ph = h ? 0.f : 1.f;        // phantom v=7 killer (h=1,s=3)
    h2 A0[14], A1[14];
    #pragma unroll
    for (int i = 0; i < 14; ++i) {
        A0[i] = (h2){(__fp16)0.f, (__fp16)0.f};
        A1[i] = (h2){(__fp16)0.f, (__fp16)0.f};
    }

    // per-slot tap body: 28 taps (h=1 phantom killed), f32 math, f16 pack,
    // pair-shfl denom, pk_fma accumulate. Identical numerics to prev version.
    auto tap_slot = [&](int cb, h2* Acc, float cpk, const float2* buf) {
        const float2 cpair = buf[cb + R_ * PSTR + R_];
        const int bh = cb + h;
        h2 ex[14];
        float dsum = 0.f;
        #pragma unroll
        for (int u = 0; u < D_; ++u) {
            #pragma unroll
            for (int m = 0; m < 2; ++m) {
                const float2 np0 = buf[bh + u * PSTR + 4 * m];
                const float2 np1 = buf[bh + u * PSTR + 4 * m + 2];
                float t0 = fmaxf(cpair.x * np0.y, np0.x * cpair.y);
                float t1 = fmaxf(cpair.x * np1.y, np1.x * cpair.y);
                if (m == 1) t1 *= ph;   // kill phantom v=7 (reads REAL data!)
                dsum += t0;
                dsum += t1;
                ex[u * 2 + m] = __builtin_amdgcn_cvt_pkrtz(t0, t1);
            }
        }
        const float denom = dsum + __shfl_xor(dsum, 1, 64);  // lane pair = slot
        const float scale = cpk * __frcp_rn(denom);          // denom >= 1
        const h2 s2 = __builtin_amdgcn_cvt_pkrtz(scale, scale);
        #pragma unroll
        for (int m = 0; m < 14; ++m) Acc[m] = ex[m] * s2 + Acc[m];
    };

    int p = 0;
    for (int k = k0; k < k1; ++k) {
        const float cpk = cp[k];
        const float2* buf = patch2[p];
        const float c0 = pr0, c1 = pr1;    // raw*swt for k+1 (if any)
        if (k + 2 < k1) {                  // issue k+2 loads before taps
            const float* fn = fb + (size_t)(k + 2) * NN;
            pr0 = fn[soff[0]] * swt[0];
            pr1 = fn[soff[1]] * swt[1];
        }

        if (act0) tap_slot(cb0, A0, cpk, buf);
        if (act1) tap_slot(cb1, A1, cpk, buf);

        if (k + 1 < k1) {                  // stage k+1 into alternate buffer
            float2* nb = patch2[p ^ 1];
            nb[slds[0]] = make_float2(ozw[0] * exp2f(c0), ozw[0] * exp2f(-c0));
            nb[slds[1]] = make_float2(ozw[1] * exp2f(c1), ozw[1] * exp2f(-c1));
        }
        __syncthreads();
        p ^= 1;
    }

    // epilogue: pixels in plist are masked by construction -> no mask check
    auto emit = [&](int pg, const h2* Acc) {
        // w = u*7 + 2s + h; s=2m -> offset 4m; s=2m+1 -> offset 4m+2
        float* ab = Aout + (size_t)b * W_ * NN + h * NN + pg;
        #pragma unroll
        for (int u = 0; u < D_; ++u) {
            #pragma unroll
            for (int m = 0; m < 2; ++m) {
                const h2 tv = Acc[u * 2 + m];
                atomicAdd(ab + (u * D_ + 4 * m) * NN, (float)tv[0]);
                if (h == 0 || m < 1)   // h=1,m=1 second tap = phantom v=7
                    atomicAdd(ab + (u * D_ + 4 * m + 2) * NN, (float)tv[1]);
            }
        }
    };
    if (act0) emit(pg0, A0);
    if (act1) emit(pg1, A1);
}

// Gather: out[b,q,c] = sum_w A[b,w,p]*x2[b,c,p], p=q-(u-3,v-3), w=u*7+v.
// Block = 64 q x 8 w-groups (512 thr); wg owns u=wg (wg=7 idle in taps).
// 21 c-accumulators in registers; LDS reduce over 8 planes; contiguous store.
#define RSTR 22   // LDS reduce stride
__global__ __launch_bounds__(512, 4) void rwn_gather(
    const float* __restrict__ Aarr,  // [B,W,NN]
    const float* __restrict__ x2,    // [B,C,NN]
    float* __restrict__ out)         // [B,NN,C]
{
    __shared__ float red[8 * 64 * RSTR];   // 45056 B

    const int q0 = blockIdx.x * 64;
    const int b  = blockIdx.y;
    const int tid = threadIdx.x;
    const int qh = tid & 63;         // lane -> consecutive q (coalesced)
    const int wg = tid >> 6;         // wave-uniform w-group = u
    const int q = q0 + qh;
    const int i = q >> 7, j = q & (N_ - 1);

    const float* Ab = Aarr + (size_t)b * W_ * NN;
    const float* xb = x2 + (size_t)b * C_ * NN;

    float acc[C_];
    #pragma unroll
    for (int c = 0; c < C_; ++c) acc[c] = 0.f;

    if (wg < D_) {
        const int pi = i - (wg - R_);
        const int cpi = pi < 0 ? 0 : (pi > N_ - 1 ? N_ - 1 : pi);
        const float rv = (pi >= 0 && pi < N_) ? 1.f : 0.f;
        const float* Aw = Ab + (size_t)wg * D_ * NN;
        #pragma unroll
        for (int v = 0; v < D_; ++v) {
            const int pj = j - (v - R_);
            const int cpj = pj < 0 ? 0 : (pj > N_ - 1 ? N_ - 1 : pj);
            const float vv = (pj >= 0 && pj < N_) ? rv : 0.f;
            const int p = cpi * N_ + cpj;
            const float a = vv * Aw[(size_t)v * NN + p];
            #pragma unroll
            for (int c = 0; c < C_; ++c)
                acc[c] += a * xb[(size_t)c * NN + p];
        }
    }

    // stage per-wg partials
    float* rbase = red + (wg * 64 + qh) * RSTR;
    #pragma unroll
    for (int c = 0; c < C_; ++c) rbase[c] = acc[c];
    __syncthreads();

    // reduce 8 planes, store contiguous (64*21 = 1344 floats)
    float* ob = out + ((size_t)b * NN + q0) * C_;
    for (int e = tid; e < 64 * C_; e += 512) {
        const int qq = e / C_, cc = e - qq * C_;
        const int a = qq * RSTR + cc;
        float s = 0.f;
        #pragma unroll
        for (int pl = 0; pl < 8; ++pl)
            s += red[pl * 64 * RSTR + a];
        ob[e] = s;
    }
}

extern "C" void kernel_launch(void* const* d_in, const int* in_sizes, int n_in,
                              void* d_out, int out_size, void* d_ws, size_t ws_size,
                              hipStream_t stream) {
    const float* feats = (const float*)d_in[0];   // [B,K,N,N]
    const float* x2    = (const float*)d_in[1];   // [B,C,NN]
    const int*   mask  = (const int*)d_in[2];     // [B,N,N]
    const float* cp    = (const float*)d_in[3];   // [K]
    float* out = (float*)d_out;

    float* Aarr = (float*)d_ws;                   // [B,W,NN] fp32
    const size_t Abytes = (size_t)B_ * W_ * NN * sizeof(float);

    (void)hipMemsetAsync(Aarr, 0, Abytes, stream);

    dim3 gridA(64, KC, B_);
    rwn_affinity<<<gridA, 256, 0, stream>>>(feats, mask, cp, Aarr);

    dim3 gridG(NN / 64, B_);
    rwn_gather<<<gridG, 512, 0, stream>>>(Aarr, x2, out);
}